// Round 7
// baseline (139.768 us; speedup 1.0000x reference)
//
#include <hip/hip_runtime.h>
#include <hip/hip_bf16.h>

typedef short bf16x8 __attribute__((ext_vector_type(8)));
typedef float f32x4 __attribute__((ext_vector_type(4)));

#define N_IMG 64
#define CIN   256
#define COUT  256
#define HH    28
#define WW    28
#define PH    30
#define PW    30
#define M_TOT (N_IMG*HH*WW)          // 50176
#define OUT_ELEMS (N_IMG*COUT*HH*WW) // 12845056

// workspace layout (bytes)
#define XT_ELEMS   ((size_t)N_IMG*PH*PW*CIN)       // 14745600 bf16
#define WT_OFF     (XT_ELEMS*2)                    // 29491200
#define WT_ELEMS   ((size_t)9*COUT*CIN)            // 589824 bf16
#define BQ_OFF     (WT_OFF + WT_ELEMS*2)           // 30670848

#define GLD16(g, l) __builtin_amdgcn_global_load_lds( \
    (const __attribute__((address_space(1))) void*)(g), \
    (__attribute__((address_space(3))) void*)(l), 16, 0, 0)

// ---------------------------------------------------------------------------
// Kernel 1: x int32 NCHW -> padded bf16 NHWC [N][30][30][256]
__global__ __launch_bounds__(256) void transform_x(const int* __restrict__ xq,
                                                   unsigned short* __restrict__ xt) {
    __shared__ float xs[CIN*29];   // padded stride 29 -> no bank conflicts
    const int b = blockIdx.x;
    const int n = b / PH, py = b % PH;
    const int t = threadIdx.x;
    unsigned short* dst = xt + ((size_t)(n*PH + py))*PW*CIN;
    if (py == 0 || py == PH-1) {
        for (int i = t; i < PW*CIN; i += 256) dst[i] = 0;
        return;
    }
    const int h = py - 1;
    const int* src = xq + (size_t)n*CIN*HH*WW + h*WW;
    for (int i = t; i < CIN*WW; i += 256) {
        const int ci = i / WW, w = i % WW;
        xs[ci*29 + w] = (float)src[ci*HH*WW + w];
    }
    __syncthreads();
    for (int i = t; i < PW*CIN; i += 256) {
        const int px = i / CIN, ci = i % CIN;
        float v = (px == 0 || px == PW-1) ? 0.f : xs[ci*29 + (px-1)];
        dst[px*CIN + ci] = (unsigned short)(__float_as_uint(v) >> 16);
    }
}

// ---------------------------------------------------------------------------
// Kernel 2: per-channel weight quant + bias quant + scale_out to d_out tail.
// wt layout: [tap(9)][co(256)][ci(256)] bf16   (values in [-128,127], exact)
__global__ __launch_bounds__(256) void quant_w(const float* __restrict__ weight,
                                               const float* __restrict__ scale_x,
                                               const float* __restrict__ bias,
                                               unsigned short* __restrict__ wt,
                                               int* __restrict__ bq,
                                               float* __restrict__ out_tail) {
    __shared__ float red[256];
    const int co = blockIdx.x, t = threadIdx.x;
    const float* wrow = weight + (size_t)co*CIN*9;
    float wv[9];
    float mx = 0.f;
    for (int it = 0; it < 9; ++it) {
        float v = wrow[it*256 + t];
        wv[it] = v;
        mx = fmaxf(mx, fabsf(v));
    }
    red[t] = mx;
    __syncthreads();
    for (int s = 128; s > 0; s >>= 1) {
        if (t < s) red[t] = fmaxf(red[t], red[t+s]);
        __syncthreads();
    }
    const float scale = fmaxf(red[0], 1e-8f) / 127.f;
    for (int it = 0; it < 9; ++it) {
        const int i = it*256 + t;          // index over [ci][r][s]
        const int ci = i / 9, rs = i % 9;
        float q = rintf(wv[it] / scale);   // rintf = round-half-even = jnp.round
        q = fminf(fmaxf(q, -128.f), 127.f);
        wt[((size_t)rs*COUT + co)*CIN + ci] = (unsigned short)(__float_as_uint(q) >> 16);
    }
    if (t == 0) {
        const float so = scale * scale_x[0];
        out_tail[co] = so;
        bq[co] = (int)rintf(bias[co] / so);
    }
}

// ---------------------------------------------------------------------------
// Kernel 3: implicit-GEMM conv, BM=256 x BN=256 x BK=32, 512 thr / 8 waves
// (2 co x 4 m), per-wave 128x64 = acc[8][4], 32 MFMA + 12 ds_read_b128 per
// K-tile per wave. 72 K-tiles (9 taps x 8 ci-chunks).
// LDS: 3 buffers x (A 16KB + B 16KB) = 96KB. Chunked layout [kc(4)][row(256)]
// [8 bf16]: global_load_lds dest stays linear AND frag ds_read_b128 is
// conflict-free (bank quad = row&7 -> 2 lanes/quad; measured 0 conflicts in
// this layout at rounds 1/4). Pipeline: 2 tiles prefetched ahead; ONE raw
// s_barrier per K-tile with counted s_waitcnt vmcnt(4) (never 0 in the main
// loop, T4) -- the wait for tile t lands ~2 compute phases after issue.
// T5 setprio around the MFMA cluster.
__global__ __launch_bounds__(512, 1) void conv_mfma(const unsigned short* __restrict__ xt,
                                                    const unsigned short* __restrict__ wt,
                                                    const int* __restrict__ bq,
                                                    float* __restrict__ out) {
    __shared__ short Ash[3*8192];   // [buf][kc4][row256][8]
    __shared__ short Bsh[3*8192];
    const int d = threadIdx.x;
    const int w8 = d >> 6;                   // wave id 0..7
    const int lane = d & 63, lr = lane & 15, kg = lane >> 4;
    const int wm = w8 >> 2, wn = w8 & 3;     // wave grid: 2 (co) x 4 (m)
    const int m0 = blockIdx.x << 8;

    // ---- staging: thread d covers row sr = d&255, k-subchunks kc = (d>>8)+2q
    const int sr  = d & 255;
    const int sk8 = (d >> 8) << 3;           // element offset 0 or 8
    const unsigned short* aS = wt + sr*CIN + sk8;
    const unsigned short* bS;
    {
        const int m = m0 + sr;
        const int n = m / 784, hw = m % 784, h = hw / 28, wq = hw % 28;
        bS = xt + ((size_t)((n*PH + h)*PW + wq))*CIN + sk8;
    }
    const int dstw = w8 << 9;                // wave-uniform LDS base (shorts)

    f32x4 acc[8][4] = {};

    // frag read bases (shorts): kg*2048 + row*8
    const int arb = kg*2048 + (wm*128 + lr)*8;
    const int brb = kg*2048 + (wn*64  + lr)*8;

#define STAGE(T_, P_) do { \
    const int tap_ = (T_) >> 3, c_ = (T_) & 7; \
    const int r3_ = (tap_*171) >> 9; \
    const int ao_ = (tap_ << 16) + (c_ << 5); \
    const int bo_ = ((r3_*PW + (tap_ - r3_*3)) << 8) + (c_ << 5); \
    GLD16(aS + ao_,      Ash + (P_)*8192 + dstw); \
    GLD16(aS + ao_ + 16, Ash + (P_)*8192 + 4096 + dstw); \
    GLD16(bS + bo_,      Bsh + (P_)*8192 + dstw); \
    GLD16(bS + bo_ + 16, Bsh + (P_)*8192 + 4096 + dstw); \
} while (0)

#define COMPUTE(P_) do { \
    const short* A_ = Ash + (P_)*8192; \
    const short* B_ = Bsh + (P_)*8192; \
    bf16x8 af[8], bf[4]; \
    _Pragma("unroll") \
    for (int mr = 0; mr < 8; ++mr) af[mr] = *(const bf16x8*)&A_[arb + mr*128]; \
    _Pragma("unroll") \
    for (int nr = 0; nr < 4; ++nr) bf[nr] = *(const bf16x8*)&B_[brb + nr*128]; \
    __builtin_amdgcn_s_setprio(1); \
    _Pragma("unroll") \
    for (int mr = 0; mr < 8; ++mr) \
        _Pragma("unroll") \
        for (int nr = 0; nr < 4; ++nr) \
            acc[mr][nr] = __builtin_amdgcn_mfma_f32_16x16x32_bf16( \
                af[mr], bf[nr], acc[mr][nr], 0, 0, 0); \
    __builtin_amdgcn_s_setprio(0); \
} while (0)

#define SYNCN(N_) do { \
    asm volatile("s_waitcnt vmcnt(" #N_ ")" ::: "memory"); \
    __builtin_amdgcn_s_barrier(); \
    __builtin_amdgcn_sched_barrier(0); \
} while (0)

    STAGE(0, 0);
    STAGE(1, 1);
#pragma unroll 1
    for (int tt = 0; tt < 69; tt += 3) {
        SYNCN(4); STAGE(tt + 2, 2); COMPUTE(0);   // tile tt
        SYNCN(4); STAGE(tt + 3, 0); COMPUTE(1);   // tile tt+1
        SYNCN(4); STAGE(tt + 4, 1); COMPUTE(2);   // tile tt+2
    }
    // tail: tiles 69,70,71 (staged through 70 by the loop)
    SYNCN(4); STAGE(71, 2); COMPUTE(0);           // tile 69
    SYNCN(4); COMPUTE(1);                         // tile 70
    SYNCN(0); COMPUTE(2);                         // tile 71

    // epilogue: D row = co (kg*4+rg), col = m (lr); 64B coalesced runs
#pragma unroll
    for (int nr = 0; nr < 4; ++nr) {
        const int mm = m0 + wn*64 + nr*16 + lr;
        const int nn = mm / 784, hw2 = mm % 784;
        float* orow = out + (size_t)nn*COUT*784 + hw2;
#pragma unroll
        for (int mr = 0; mr < 8; ++mr) {
            const int co = wm*128 + mr*16 + kg*4;
#pragma unroll
            for (int rg = 0; rg < 4; ++rg)
                orow[(size_t)(co + rg)*784] = acc[mr][nr][rg] + (float)bq[co + rg];
        }
    }
#undef STAGE
#undef COMPUTE
#undef SYNCN
}

// ---------------------------------------------------------------------------
extern "C" void kernel_launch(void* const* d_in, const int* in_sizes, int n_in,
                              void* d_out, int out_size, void* d_ws, size_t ws_size,
                              hipStream_t stream) {
    const int*   xq      = (const int*)d_in[0];
    const float* scale_x = (const float*)d_in[1];
    const float* weight  = (const float*)d_in[2];
    const float* bias    = (const float*)d_in[3];
    float* out = (float*)d_out;

    unsigned short* xt = (unsigned short*)d_ws;
    unsigned short* wt = (unsigned short*)((char*)d_ws + WT_OFF);
    int*            bq = (int*)((char*)d_ws + BQ_OFF);

    hipLaunchKernelGGL(transform_x, dim3(N_IMG*PH), dim3(256), 0, stream, xq, xt);
    hipLaunchKernelGGL(quant_w, dim3(COUT), dim3(256), 0, stream,
                       weight, scale_x, bias, wt, bq, out + OUT_ELEMS);
    hipLaunchKernelGGL(conv_mfma, dim3(M_TOT/256), dim3(512), 0, stream,
                       xt, wt, bq, out);
}

// Round 8
// 132.709 us; speedup vs baseline: 1.0532x; 1.0532x over previous
//
#include <hip/hip_runtime.h>
#include <hip/hip_bf16.h>

typedef short bf16x8 __attribute__((ext_vector_type(8)));
typedef float f32x4 __attribute__((ext_vector_type(4)));

#define N_IMG 64
#define CIN   256
#define COUT  256
#define HH    28
#define WW    28
#define PH    30
#define PW    30
#define M_TOT (N_IMG*HH*WW)          // 50176
#define OUT_ELEMS (N_IMG*COUT*HH*WW) // 12845056

// workspace layout (bytes)
#define XT_ELEMS   ((size_t)N_IMG*PH*PW*CIN)       // 14745600 bf16
#define WT_OFF     (XT_ELEMS*2)                    // 29491200
#define WT_ELEMS   ((size_t)9*COUT*CIN)            // 589824 bf16
#define BQ_OFF     (WT_OFF + WT_ELEMS*2)           // 30670848

#define GLD16(g, l) __builtin_amdgcn_global_load_lds( \
    (const __attribute__((address_space(1))) void*)(g), \
    (__attribute__((address_space(3))) void*)(l), 16, 0, 0)

// ---------------------------------------------------------------------------
// Kernel 1: x int32 NCHW -> padded bf16 NHWC [N][30][30][256]
__global__ __launch_bounds__(256) void transform_x(const int* __restrict__ xq,
                                                   unsigned short* __restrict__ xt) {
    __shared__ float xs[CIN*29];   // padded stride 29 -> no bank conflicts
    const int b = blockIdx.x;
    const int n = b / PH, py = b % PH;
    const int t = threadIdx.x;
    unsigned short* dst = xt + ((size_t)(n*PH + py))*PW*CIN;
    if (py == 0 || py == PH-1) {
        for (int i = t; i < PW*CIN; i += 256) dst[i] = 0;
        return;
    }
    const int h = py - 1;
    const int* src = xq + (size_t)n*CIN*HH*WW + h*WW;
    for (int i = t; i < CIN*WW; i += 256) {
        const int ci = i / WW, w = i % WW;
        xs[ci*29 + w] = (float)src[ci*HH*WW + w];
    }
    __syncthreads();
    for (int i = t; i < PW*CIN; i += 256) {
        const int px = i / CIN, ci = i % CIN;
        float v = (px == 0 || px == PW-1) ? 0.f : xs[ci*29 + (px-1)];
        dst[px*CIN + ci] = (unsigned short)(__float_as_uint(v) >> 16);
    }
}

// ---------------------------------------------------------------------------
// Kernel 2: per-channel weight quant + bias quant + scale_out to d_out tail.
// wt layout: [tap(9)][co(256)][ci(256)] bf16   (values in [-128,127], exact)
__global__ __launch_bounds__(256) void quant_w(const float* __restrict__ weight,
                                               const float* __restrict__ scale_x,
                                               const float* __restrict__ bias,
                                               unsigned short* __restrict__ wt,
                                               int* __restrict__ bq,
                                               float* __restrict__ out_tail) {
    __shared__ float red[256];
    const int co = blockIdx.x, t = threadIdx.x;
    const float* wrow = weight + (size_t)co*CIN*9;
    float wv[9];
    float mx = 0.f;
    for (int it = 0; it < 9; ++it) {
        float v = wrow[it*256 + t];
        wv[it] = v;
        mx = fmaxf(mx, fabsf(v));
    }
    red[t] = mx;
    __syncthreads();
    for (int s = 128; s > 0; s >>= 1) {
        if (t < s) red[t] = fmaxf(red[t], red[t+s]);
        __syncthreads();
    }
    const float scale = fmaxf(red[0], 1e-8f) / 127.f;
    for (int it = 0; it < 9; ++it) {
        const int i = it*256 + t;          // index over [ci][r][s]
        const int ci = i / 9, rs = i % 9;
        float q = rintf(wv[it] / scale);   // rintf = round-half-even = jnp.round
        q = fminf(fmaxf(q, -128.f), 127.f);
        wt[((size_t)rs*COUT + co)*CIN + ci] = (unsigned short)(__float_as_uint(q) >> 16);
    }
    if (t == 0) {
        const float so = scale * scale_x[0];
        out_tail[co] = so;
        bq[co] = (int)rintf(bias[co] / so);
    }
}

// ---------------------------------------------------------------------------
// Kernel 3: implicit-GEMM conv, 8-phase-style fine interleave (T3+T4+T5).
//   C[co][m] = sum_{tap,ci} W[co][ci,tap] * X[ci,tap][m]
// BM=256 x BN=256 x BK=32, 512 thr / 8 waves (2 co x 4 m), per-wave 128x64,
// acc[8][4]. 72 K-tiles. LDS: FOUR buffers x (A 16KB + B 16KB) = 128KB,
// chunked [kc(4)][row(256)][8] (linear for global_load_lds, 0 bank conflicts
// measured). Pipeline: stages issued 3 tiles ahead (2 gld_lds per sub-phase);
// per tile TWO sub-phases, each {ds_read subtile, stage, barrier, lgkmcnt(0),
// setprio(1), 16 MFMA, setprio(0), barrier}; ONE counted s_waitcnt vmcnt(8)
// per tile (never 0 in main loop) -- tile t's loads issued ~2 tiles (~1500cy)
// before their gate.
__global__ __launch_bounds__(512, 1) void conv_mfma(const unsigned short* __restrict__ xt,
                                                    const unsigned short* __restrict__ wt,
                                                    const int* __restrict__ bq,
                                                    float* __restrict__ out) {
    __shared__ short Ash[4*8192];   // [buf][kc4][row256][8]
    __shared__ short Bsh[4*8192];
    const int d = threadIdx.x;
    const int w8 = d >> 6;                   // wave id 0..7
    const int lane = d & 63, lr = lane & 15, kg = lane >> 4;
    const int wm = w8 >> 2, wn = w8 & 3;     // wave grid: 2 (co) x 4 (m)
    const int m0 = blockIdx.x << 8;

    // staging: thread d covers row sr = d&255, k-subchunk kc = (d>>8) (+2 for
    // the second load of each operand)
    const int sr  = d & 255;
    const int sk8 = (d >> 8) << 3;           // element offset 0 or 8
    const unsigned short* aS = wt + sr*CIN + sk8;
    const unsigned short* bS;
    {
        const int m = m0 + sr;
        const int n = m / 784, hw = m % 784, h = hw / 28, wq = hw % 28;
        bS = xt + ((size_t)((n*PH + h)*PW + wq))*CIN + sk8;
    }
    const int dstw = w8 << 9;                // wave-uniform LDS base (shorts)

    f32x4 acc[8][4] = {};

    // frag read bases (shorts): kc(=kg)*2048 + row*8
    const int arb = kg*2048 + (wm*128 + lr)*8;
    const int brb = kg*2048 + (wn*64  + lr)*8;

#define STAGE_A(T_) do { \
    const int tap_ = (T_) >> 3, c_ = (T_) & 7, p_ = (T_) & 3; \
    const int ao_ = (tap_ << 16) + (c_ << 5); \
    GLD16(aS + ao_,      Ash + p_*8192 + dstw); \
    GLD16(aS + ao_ + 16, Ash + p_*8192 + 4096 + dstw); \
} while (0)

#define STAGE_B(T_) do { \
    const int tap_ = (T_) >> 3, c_ = (T_) & 7, p_ = (T_) & 3; \
    const int r3_ = (tap_*171) >> 9; \
    const int bo_ = ((r3_*PW + (tap_ - r3_*3)) << 8) + (c_ << 5); \
    GLD16(bS + bo_,      Bsh + p_*8192 + dstw); \
    GLD16(bS + bo_ + 16, Bsh + p_*8192 + 4096 + dstw); \
} while (0)

#define GATEN(N_) asm volatile("s_waitcnt vmcnt(" #N_ ")" ::: "memory")
#define LGKM0()   do { asm volatile("s_waitcnt lgkmcnt(0)" ::: "memory"); \
                       __builtin_amdgcn_sched_barrier(0); } while (0)

// One K-tile = two sub-phases of {reads | stage | bar | wait | 16 MFMA | bar}.
#define TILE(BUF_, T3_, DOSTAGE_, GATE_) do { \
    const short* A_ = Ash + (BUF_)*8192; \
    const short* B_ = Bsh + (BUF_)*8192; \
    bf16x8 af[8], bf[4]; \
    _Pragma("unroll") \
    for (int mr = 0; mr < 4; ++mr) af[mr] = *(const bf16x8*)&A_[arb + mr*128]; \
    _Pragma("unroll") \
    for (int nr = 0; nr < 4; ++nr) bf[nr] = *(const bf16x8*)&B_[brb + nr*128]; \
    if (DOSTAGE_) STAGE_A(T3_); \
    __builtin_amdgcn_s_barrier(); \
    LGKM0(); \
    __builtin_amdgcn_s_setprio(1); \
    _Pragma("unroll") \
    for (int mr = 0; mr < 4; ++mr) \
        _Pragma("unroll") \
        for (int nr = 0; nr < 4; ++nr) \
            acc[mr][nr] = __builtin_amdgcn_mfma_f32_16x16x32_bf16( \
                af[mr], bf[nr], acc[mr][nr], 0, 0, 0); \
    __builtin_amdgcn_s_setprio(0); \
    __builtin_amdgcn_s_barrier(); \
    _Pragma("unroll") \
    for (int mr = 4; mr < 8; ++mr) af[mr] = *(const bf16x8*)&A_[arb + mr*128]; \
    if (DOSTAGE_) STAGE_B(T3_); \
    GATE_; \
    __builtin_amdgcn_s_barrier(); \
    LGKM0(); \
    __builtin_amdgcn_s_setprio(1); \
    _Pragma("unroll") \
    for (int mr = 4; mr < 8; ++mr) \
        _Pragma("unroll") \
        for (int nr = 0; nr < 4; ++nr) \
            acc[mr][nr] = __builtin_amdgcn_mfma_f32_16x16x32_bf16( \
                af[mr], bf[nr], acc[mr][nr], 0, 0, 0); \
    __builtin_amdgcn_s_setprio(0); \
    __builtin_amdgcn_s_barrier(); \
} while (0)

    // prologue: stage tiles 0,1,2; gate tile 0 landed (12 -> <=8 outstanding)
    STAGE_A(0); STAGE_B(0);
    STAGE_A(1); STAGE_B(1);
    STAGE_A(2); STAGE_B(2);
    GATEN(8);
    __builtin_amdgcn_s_barrier();

#pragma unroll 1
    for (int t = 0; t < 68; t += 4) {        // tiles 0..67, staging t+3..t+6
        TILE(0, t + 3, 1, GATEN(8));
        TILE(1, t + 4, 1, GATEN(8));
        TILE(2, t + 5, 1, GATEN(8));
        TILE(3, t + 6, 1, GATEN(8));
    }
    TILE(0, 71, 1, GATEN(8));                // tile 68 (stages 71 -> buf 3)
    TILE(1, 0, 0, GATEN(4));                 // tile 69
    TILE(2, 0, 0, GATEN(0));                 // tile 70
    TILE(3, 0, 0, (void)0);                  // tile 71

    // epilogue: D row = co (kg*4+rg), col = m (lr); 64B coalesced runs
#pragma unroll
    for (int nr = 0; nr < 4; ++nr) {
        const int mm = m0 + wn*64 + nr*16 + lr;
        const int nn = mm / 784, hw2 = mm % 784;
        float* orow = out + (size_t)nn*COUT*784 + hw2;
#pragma unroll
        for (int mr = 0; mr < 8; ++mr) {
            const int co = wm*128 + mr*16 + kg*4;
#pragma unroll
            for (int rg = 0; rg < 4; ++rg)
                orow[(size_t)(co + rg)*784] = acc[mr][nr][rg] + (float)bq[co + rg];
        }
    }
#undef STAGE_A
#undef STAGE_B
#undef GATEN
#undef LGKM0
#undef TILE
}

// ---------------------------------------------------------------------------
extern "C" void kernel_launch(void* const* d_in, const int* in_sizes, int n_in,
                              void* d_out, int out_size, void* d_ws, size_t ws_size,
                              hipStream_t stream) {
    const int*   xq      = (const int*)d_in[0];
    const float* scale_x = (const float*)d_in[1];
    const float* weight  = (const float*)d_in[2];
    const float* bias    = (const float*)d_in[3];
    float* out = (float*)d_out;

    unsigned short* xt = (unsigned short*)d_ws;
    unsigned short* wt = (unsigned short*)((char*)d_ws + WT_OFF);
    int*            bq = (int*)((char*)d_ws + BQ_OFF);

    hipLaunchKernelGGL(transform_x, dim3(N_IMG*PH), dim3(256), 0, stream, xq, xt);
    hipLaunchKernelGGL(quant_w, dim3(COUT), dim3(256), 0, stream,
                       weight, scale_x, bias, wt, bq, out + OUT_ELEMS);
    hipLaunchKernelGGL(conv_mfma, dim3(M_TOT/256), dim3(512), 0, stream,
                       xt, wt, bq, out);
}

// Round 9
// 98.885 us; speedup vs baseline: 1.4134x; 1.3421x over previous
//
#include <hip/hip_runtime.h>
#include <hip/hip_bf16.h>

typedef int   i32x4 __attribute__((ext_vector_type(4)));

#define N_IMG 64
#define CIN   256
#define COUT  256
#define HH    28
#define WW    28
#define PH    30
#define PW    30
#define M_TOT (N_IMG*HH*WW)          // 50176
#define OUT_ELEMS (N_IMG*COUT*HH*WW) // 12845056

// workspace layout (bytes) — all int8 now
#define XT_BYTES   ((size_t)N_IMG*PH*PW*CIN)       // 14745600
#define WT_OFF     (XT_BYTES)
#define WT_BYTES   ((size_t)9*COUT*CIN)            // 589824
#define BQ_OFF     (WT_OFF + WT_BYTES)             // 15335424

#define GLD16(g, l) __builtin_amdgcn_global_load_lds( \
    (const __attribute__((address_space(1))) void*)(g), \
    (__attribute__((address_space(3))) void*)(l), 16, 0, 0)

// ---------------------------------------------------------------------------
// Kernel 1: x int32 NCHW -> padded int8 NHWC [N][30][30][256], value x-127,
// PAD = -127  (so conv_i8 + 127*sum(w) == true conv with zero-padding).
__global__ __launch_bounds__(256) void transform_x(const int* __restrict__ xq,
                                                   signed char* __restrict__ xt) {
    __shared__ int xs[CIN*29];     // padded stride 29 -> no bank conflicts
    const int b = blockIdx.x;
    const int n = b / PH, py = b % PH;
    const int t = threadIdx.x;
    signed char* dst = xt + ((size_t)(n*PH + py))*PW*CIN;
    if (py == 0 || py == PH-1) {
        for (int i = t; i < PW*CIN; i += 256) dst[i] = -127;
        return;
    }
    const int h = py - 1;
    const int* src = xq + (size_t)n*CIN*HH*WW + h*WW;
    for (int i = t; i < CIN*WW; i += 256) {
        const int ci = i / WW, w = i % WW;
        xs[ci*29 + w] = src[ci*HH*WW + w];
    }
    __syncthreads();
    for (int i = t; i < PW*CIN; i += 256) {
        const int px = i / CIN, ci = i % CIN;
        const int v = (px == 0 || px == PW-1) ? 0 : xs[ci*29 + (px-1)];
        dst[px*CIN + ci] = (signed char)(v - 127);
    }
}

// ---------------------------------------------------------------------------
// Kernel 2: per-channel weight quant (int8) + bias quant + scale_out.
// wt layout: [tap(9)][co(256)][ci(256)] int8.  bq[co] folds in the +127*S
// correction for the x-shift (S = sum of all w_q for channel co).
__global__ __launch_bounds__(256) void quant_w(const float* __restrict__ weight,
                                               const float* __restrict__ scale_x,
                                               const float* __restrict__ bias,
                                               signed char* __restrict__ wt,
                                               int* __restrict__ bq,
                                               float* __restrict__ out_tail) {
    __shared__ float red[256];
    __shared__ int  sred[256];
    const int co = blockIdx.x, t = threadIdx.x;
    const float* wrow = weight + (size_t)co*CIN*9;
    float wv[9];
    float mx = 0.f;
    for (int it = 0; it < 9; ++it) {
        float v = wrow[it*256 + t];
        wv[it] = v;
        mx = fmaxf(mx, fabsf(v));
    }
    red[t] = mx;
    __syncthreads();
    for (int s = 128; s > 0; s >>= 1) {
        if (t < s) red[t] = fmaxf(red[t], red[t+s]);
        __syncthreads();
    }
    const float scale = fmaxf(red[0], 1e-8f) / 127.f;
    int isum = 0;
    for (int it = 0; it < 9; ++it) {
        const int i = it*256 + t;          // index over [ci][r][s]
        const int ci = i / 9, rs = i % 9;
        float q = rintf(wv[it] / scale);   // rintf = round-half-even = jnp.round
        q = fminf(fmaxf(q, -128.f), 127.f);
        const int qi = (int)q;
        isum += qi;
        wt[(size_t)rs*COUT*CIN + co*CIN + ci] = (signed char)qi;
    }
    sred[t] = isum;
    __syncthreads();
    for (int s = 128; s > 0; s >>= 1) {
        if (t < s) sred[t] += sred[t+s];
        __syncthreads();
    }
    if (t == 0) {
        const float so = scale * scale_x[0];
        out_tail[co] = so;
        bq[co] = (int)rintf(bias[co] / so) + 127 * sred[0];
    }
}

// ---------------------------------------------------------------------------
// Kernel 3: implicit-GEMM conv, int8 MFMA (mfma_i32_16x16x64_i8, 2x bf16 rate,
// exact i32 accumulation).  C[co][m] = sum_{tap,ci} W * X'.
// BM=256 (all co) x BN=128 x BK=64, 512 thr / 8 waves (4 co x 2 m), per-wave
// 64x64 = acc[4][4], 16 MFMA + 8 ds_read_b128 per K-tile per wave.
// 36 K-tiles (9 taps x 4 ci-chunks).  LDS: 2 x (A 16KB + B 8KB) = 48KB ->
// TWO independent blocks/CU (grid 392) so one block's MFMA hides the other's
// staging latency (m114 overlap) — no fragile intra-block pipelining.
// Chunked LDS [kc(4)][row][16B]: linear for global_load_lds, conflict-free
// ds_read_b128 (bank quad = row&7, 2 lanes/quad; 0 conflicts measured).
// Schedule = round-6 winner: STAGE(next) -> COMPUTE(cur) -> drain+barrier.
__global__ __launch_bounds__(512, 4) void conv_mfma(const signed char* __restrict__ xt,
                                                    const signed char* __restrict__ wt,
                                                    const int* __restrict__ bq,
                                                    float* __restrict__ out) {
    __shared__ signed char Ash[2*16384];  // [buf][kc4][row256][16]
    __shared__ signed char Bsh[2*8192];   // [buf][kc4][row128][16]
    const int d = threadIdx.x;
    const int w8 = d >> 6;                   // wave id 0..7
    const int lane = d & 63, lr = lane & 15, kg = lane >> 4;
    const int wm = w8 >> 1, wn = w8 & 1;     // wave grid: 4 (co) x 2 (m)
    const int m0 = blockIdx.x << 7;          // BN=128

    // staging: A thread d -> row d&255, kc (d>>8) and (d>>8)+2 (2 loads)
    //          B thread d -> row d&127, kc (d>>7)            (1 load)
    const signed char* aS = wt + (d & 255)*CIN + ((d >> 8) << 4);
    const signed char* bS;
    {
        const int m = m0 + (d & 127);
        const int n = m / 784, hw = m % 784, h = hw / 28, wq = hw % 28;
        bS = xt + ((size_t)((n*PH + h)*PW + wq))*CIN + ((d >> 7) << 4);
    }
    const int dstw = w8 << 10;               // wave-uniform LDS byte base

    i32x4 acc[4][4] = {};

    // frag read byte bases: A: kg*4096 + row*16 ; B: kg*2048 + row*16
    const int arb = kg*4096 + (wm*64 + lr)*16;
    const int brb = kg*2048 + (wn*64 + lr)*16;

#define STAGE(T_, P_) do { \
    const int tap_ = (T_) >> 2, c_ = (T_) & 3; \
    const int r3_ = (tap_*171) >> 9; \
    const int ao_ = tap_*(COUT*CIN) + (c_ << 6); \
    const int bo_ = ((r3_*PW + (tap_ - r3_*3)) << 8) + (c_ << 6); \
    GLD16(aS + ao_,      Ash + (P_)*16384 + dstw); \
    GLD16(aS + ao_ + 32, Ash + (P_)*16384 + 8192 + dstw); \
    GLD16(bS + bo_,      Bsh + (P_)*8192 + dstw); \
} while (0)

#define COMPUTE(P_) do { \
    const signed char* A_ = Ash + (P_)*16384; \
    const signed char* B_ = Bsh + (P_)*8192; \
    i32x4 af[4], bf[4]; \
    _Pragma("unroll") \
    for (int mr = 0; mr < 4; ++mr) af[mr] = *(const i32x4*)&A_[arb + mr*256]; \
    _Pragma("unroll") \
    for (int nr = 0; nr < 4; ++nr) bf[nr] = *(const i32x4*)&B_[brb + nr*256]; \
    _Pragma("unroll") \
    for (int mr = 0; mr < 4; ++mr) \
        _Pragma("unroll") \
        for (int nr = 0; nr < 4; ++nr) \
            acc[mr][nr] = __builtin_amdgcn_mfma_i32_16x16x64_i8( \
                af[mr], bf[nr], acc[mr][nr], 0, 0, 0); \
} while (0)

#define SYNCPT() do { \
    asm volatile("s_waitcnt vmcnt(0) lgkmcnt(0)" ::: "memory"); \
    __builtin_amdgcn_s_barrier(); \
    __builtin_amdgcn_sched_barrier(0); \
} while (0)

    STAGE(0, 0);
#pragma unroll 1
    for (int tt = 0; tt < 36; tt += 2) {
        SYNCPT();                       // tile tt landed
        STAGE(tt + 1, 1);               // prefetch next into spare buffer
        COMPUTE(0);                     // tile tt
        SYNCPT();                       // tile tt+1 landed
        if (tt < 34) STAGE(tt + 2, 0);
        COMPUTE(1);                     // tile tt+1
    }

    // epilogue: D row = co (kg*4+rg), col = m (lr); 64B coalesced runs
#pragma unroll
    for (int nr = 0; nr < 4; ++nr) {
        const int mm = m0 + wn*64 + nr*16 + lr;
        const int nn = mm / 784, hw2 = mm % 784;
        float* orow = out + (size_t)nn*COUT*784 + hw2;
#pragma unroll
        for (int mr = 0; mr < 4; ++mr) {
            const int co = wm*64 + mr*16 + kg*4;
#pragma unroll
            for (int rg = 0; rg < 4; ++rg)
                orow[(size_t)(co + rg)*784] = (float)(acc[mr][nr][rg] + bq[co + rg]);
        }
    }
#undef STAGE
#undef COMPUTE
#undef SYNCPT
}

// ---------------------------------------------------------------------------
extern "C" void kernel_launch(void* const* d_in, const int* in_sizes, int n_in,
                              void* d_out, int out_size, void* d_ws, size_t ws_size,
                              hipStream_t stream) {
    const int*   xq      = (const int*)d_in[0];
    const float* scale_x = (const float*)d_in[1];
    const float* weight  = (const float*)d_in[2];
    const float* bias    = (const float*)d_in[3];
    float* out = (float*)d_out;

    signed char* xt = (signed char*)d_ws;
    signed char* wt = (signed char*)((char*)d_ws + WT_OFF);
    int*         bq = (int*)((char*)d_ws + BQ_OFF);

    hipLaunchKernelGGL(transform_x, dim3(N_IMG*PH), dim3(256), 0, stream, xq, xt);
    hipLaunchKernelGGL(quant_w, dim3(COUT), dim3(256), 0, stream,
                       weight, scale_x, bias, wt, bq, out + OUT_ELEMS);
    hipLaunchKernelGGL(conv_mfma, dim3(M_TOT/128), dim3(512), 0, stream,
                       xt, wt, bq, out);
}